// Round 4
// baseline (537.732 us; speedup 1.0000x reference)
//
#include <hip/hip_runtime.h>
#include <math.h>

#define B 32
#define N 16384
#define M 128
#define D 1024
#define L 390   // 3*M+6
#define EPSF 1e-16f

// ws layout (floats):
//   [O_OFF,  O_OFF+B*L)   o = emb@W + b
//   [S1_OFF, +B)          sum exp(z)   (atomic)
//   [S2_OFF, +B)          sum w_sh     (atomic)
//   [Z_OFF,  +B*N)        u = exp(beta*sim)
// Per-batch params (beta/g/s/gamma/knorm) are recomputed locally per block
// from o -- cheaper than a dedicated serialized launch (k1b removed).
#define O_OFF  0
#define S1_OFF (B*L)
#define S2_OFF (S1_OFF + B)
#define Z_OFF  (S2_OFF + B)

typedef float fvec4 __attribute__((ext_vector_type(4)));

__device__ __forceinline__ float softplusf(float x) {
    return x > 20.f ? x : log1pf(expf(x));
}
__device__ __forceinline__ float sigmoidf(float x) {
    return 1.f / (1.f + expf(-x));
}

// K1: o[b, l0:l0+64] = emb[b,:] @ W[:, l0:l0+64] + bias.  grid(7, B), 256 thr.
// Block x==0 also zeroes the S1/S2 accumulators for its batch.
__global__ __launch_bounds__(256) void k1_gemm(const float* __restrict__ emb,
                                               const float* __restrict__ W,
                                               const float* __restrict__ bias,
                                               float* __restrict__ ws) {
    __shared__ float embS[D];
    __shared__ float red[4][64];
    const int l0 = blockIdx.x * 64;
    const int b  = blockIdx.y;
    const int t  = threadIdx.x;
    for (int i = t; i < D; i += 256) embS[i] = emb[b * D + i];
    if (blockIdx.x == 0 && t == 0) {
        ws[S1_OFF + b] = 0.f;
        ws[S2_OFF + b] = 0.f;
    }
    __syncthreads();
    const int li = t & 63;
    const int q  = t >> 6;          // 4-way split of the D dimension
    const int l  = l0 + li;
    float partial = 0.f;
    if (l < L) {
        const float* wp = W + (size_t)(q * 256) * L + l;
        #pragma unroll 8
        for (int d = 0; d < 256; ++d) partial += embS[q * 256 + d] * wp[(size_t)d * L];
    }
    red[q][li] = partial;
    __syncthreads();
    if (t < 64 && l0 + t < L) {
        float o = red[0][t] + red[1][t] + red[2][t] + red[3][t] + bias[l0 + t];
        ws[O_OFF + b * L + l0 + t] = o;
    }
}

// K2: u[b,n] = exp(beta*cos_sim(mem[b,n,:],k)); atomic S1 += sum u.
// ROW-PER-LANE: each lane owns one full row (32 x float4 independent loads,
// k broadcast from LDS). knorm/beta computed locally per block (k1b removed).
// grid(N/256, B), 256 thr.
__global__ __launch_bounds__(256) void k2_sim(const float* __restrict__ mem,
                                              float* __restrict__ ws) {
    const int b = blockIdx.y;
    const int t = threadIdx.x;
    const int n = blockIdx.x * 256 + t;
    const int wave = t >> 6, lane = t & 63;
    __shared__ float kS[M];
    __shared__ float par[2];        // {knorm, beta}
    __shared__ float acc[4];
    const float* o = ws + O_OFF + b * L;
    if (t < M) kS[t] = o[t];
    __syncthreads();
    // local ||k|| over kS[0:128] (waves 0,1) + beta
    if (t < M) {
        float kv = kS[t];
        float sq = kv * kv;
        #pragma unroll
        for (int off = 32; off >= 1; off >>= 1) sq += __shfl_xor(sq, off, 64);
        if (lane == 0) acc[t >> 6] = sq;
    }
    __syncthreads();
    if (t == 0) {
        par[0] = sqrtf(acc[0] + acc[1]);
        par[1] = softplusf(o[M]);
    }
    __syncthreads();
    const float knorm = par[0], beta = par[1];
    const float* mp = mem + ((size_t)b * N + n) * M;

    float dot = 0.f, sq = 0.f;
    #pragma unroll 16
    for (int j = 0; j < M / 4; ++j) {
        const fvec4 mv = *(const fvec4*)(mp + j * 4);
        const fvec4 kv = *(const fvec4*)&kS[j * 4];     // LDS broadcast
        dot = fmaf(mv.x, kv.x, dot); dot = fmaf(mv.y, kv.y, dot);
        dot = fmaf(mv.z, kv.z, dot); dot = fmaf(mv.w, kv.w, dot);
        sq  = fmaf(mv.x, mv.x, sq);  sq  = fmaf(mv.y, mv.y, sq);
        sq  = fmaf(mv.z, mv.z, sq);  sq  = fmaf(mv.w, mv.w, sq);
    }
    const float sim = dot / (sqrtf(sq) * knorm + EPSF);
    const float uu  = expf(beta * sim);
    ws[Z_OFF + (size_t)b * N + n] = uu;        // fully coalesced store

    // block reduction -> S1
    float r = uu;
    #pragma unroll
    for (int off = 32; off >= 1; off >>= 1) r += __shfl_xor(r, off, 64);
    if (lane == 0) acc[wave] = r;
    __syncthreads();
    if (t == 0) atomicAdd(ws + S1_OFF + b, acc[0] + acc[1] + acc[2] + acc[3]);
}

// K3: w_sh[b,n] = (s0*wg(n-1)+s1*wg(n)+s2*wg(n+1))^gamma, stash into out's w
// region; atomic S2 += sum.  Gate params computed locally. grid(N/256, B).
__global__ __launch_bounds__(256) void k3_shsum(const float* __restrict__ w_prev,
                                                float* __restrict__ ws,
                                                float* __restrict__ out) {
    const int b = blockIdx.y;
    const int n = blockIdx.x * 256 + threadIdx.x;
    __shared__ float par[6];        // {g, s0, s1, s2, gamma, invS1}
    if (threadIdx.x == 0) {
        const float* o = ws + O_OFF + b * L;
        par[0] = sigmoidf(o[M + 1]);
        float x0 = o[M + 2], x1 = o[M + 3], x2 = o[M + 4];
        float mx = fmaxf(x0, fmaxf(x1, x2));
        float e0 = expf(x0 - mx), e1 = expf(x1 - mx), e2 = expf(x2 - mx);
        float inv = 1.f / (e0 + e1 + e2);
        par[1] = e0 * inv; par[2] = e1 * inv; par[3] = e2 * inv;
        par[4] = 1.f + softplusf(o[M + 5]);
        par[5] = 1.f / ws[S1_OFF + b];
    }
    __syncthreads();
    const float g = par[0], s0 = par[1], s1 = par[2], s2 = par[3];
    const float gamma = par[4], invS1 = par[5];
    const float* u  = ws + Z_OFF + (size_t)b * N;
    const float* wp = w_prev + (size_t)b * N;
    const int nm = (n == 0)     ? N - 1 : n - 1;
    const int np = (n == N - 1) ? 0     : n + 1;
    const float gm1 = 1.f - g;
    const float gi  = g * invS1;
    const float wgm = gi * u[nm] + gm1 * wp[nm];
    const float wg0 = gi * u[n ] + gm1 * wp[n ];
    const float wgp = gi * u[np] + gm1 * wp[np];
    const float wt  = s0 * wgm + s1 * wg0 + s2 * wgp;
    const float v = powf(wt, gamma);
    out[(size_t)b * N + n] = v;                // stash w_sh; k4 scales by invS2
    float r = v;
    #pragma unroll
    for (int off = 32; off >= 1; off >>= 1) r += __shfl_xor(r, off, 64);
    __shared__ float acc[4];
    if ((threadIdx.x & 63) == 0) acc[threadIdx.x >> 6] = r;
    __syncthreads();
    if (threadIdx.x == 0) atomicAdd(ws + S2_OFF + b, acc[0] + acc[1] + acc[2] + acc[3]);
}

// K4: wv = w_sh[n]*invS2 (finalize w); new_mem = mem*(1-wv*e)+wv*a.
// - w_sh preloaded to registers before any store to `out` (alias-free pipelining)
// - PLAIN cached load of mem (L3-resident after k2; plain load maximizes hit)
// - NT stores for new_mem (don't evict mem mid-kernel), reversed traversal
// grid(N/64, B), 256 thr = 4 waves, 16 rows/wave.
__global__ __launch_bounds__(256) void k4_write(const float* __restrict__ mem,
                                                const float* __restrict__ ws,
                                                float* __restrict__ out) {
    const int b    = blockIdx.y;
    const int n0   = (gridDim.x - 1 - blockIdx.x) * 64;   // reversed traversal
    const int t    = threadIdx.x;
    const int wave = t >> 6, lane = t & 63;
    __shared__ float eS[M], aS[M];
    if (t < M) {
        eS[t] = sigmoidf(ws[O_OFF + b * L + M + 6 + t]);
        aS[t] = ws[O_OFF + b * L + 2 * M + 6 + t];
    }
    __syncthreads();
    const float invS2 = 1.f / (ws[S2_OFF + b] + EPSF);
    float* w_out = out + (size_t)b * N;
    float* m_out = out + (size_t)B * N;
    const int col  = (lane & 31) * 4;
    const int half = lane >> 5;
    const int base = n0 + wave * 16;
    const fvec4 ev = *(const fvec4*)&eS[col];
    const fvec4 av = *(const fvec4*)&aS[col];

    // preload all w_sh for this wave's 16 rows (before any store to `out`)
    float wv[8];
    #pragma unroll
    for (int it = 0; it < 8; ++it)
        wv[it] = w_out[base + it * 2 + half] * invS2;

    #pragma unroll
    for (int it = 0; it < 8; ++it) {
        const int n = base + it * 2 + half;
        const size_t idx = ((size_t)b * N + n) * M + col;
        const fvec4 mv = *(const fvec4*)(mem + idx);   // plain load: hit L3
        const float w = wv[it];
        fvec4 r;
        r.x = fmaf(mv.x, fmaf(-w, ev.x, 1.f), w * av.x);
        r.y = fmaf(mv.y, fmaf(-w, ev.y, 1.f), w * av.y);
        r.z = fmaf(mv.z, fmaf(-w, ev.z, 1.f), w * av.z);
        r.w = fmaf(mv.w, fmaf(-w, ev.w, 1.f), w * av.w);
        __builtin_nontemporal_store(r, (fvec4*)(m_out + idx));
    }

    // finalize w (tiny region: plain cached stores, full lines form in L2)
    if ((lane & 31) == 0) {
        #pragma unroll
        for (int it = 0; it < 8; ++it)
            w_out[base + it * 2 + half] = wv[it];
    }
}

extern "C" void kernel_launch(void* const* d_in, const int* in_sizes, int n_in,
                              void* d_out, int out_size, void* d_ws, size_t ws_size,
                              hipStream_t stream) {
    const float* emb    = (const float*)d_in[0];
    const float* w_prev = (const float*)d_in[1];
    const float* mem    = (const float*)d_in[2];
    const float* W      = (const float*)d_in[3];
    const float* bias   = (const float*)d_in[4];
    float* ws  = (float*)d_ws;    // needs (B*L + 2*B + B*N)*4 ≈ 2.15 MB
    float* out = (float*)d_out;

    k1_gemm <<<dim3(7, B),       256, 0, stream>>>(emb, W, bias, ws);
    k2_sim  <<<dim3(N / 256, B), 256, 0, stream>>>(mem, ws);
    k3_shsum<<<dim3(N / 256, B), 256, 0, stream>>>(w_prev, ws, out);
    k4_write<<<dim3(N / 64, B),  256, 0, stream>>>(mem, ws, out);
}